// Round 4
// baseline (111.005 us; speedup 1.0000x reference)
//
#include <hip/hip_runtime.h>
#include <stdint.h>

typedef float f32x4 __attribute__((ext_vector_type(4)));
typedef unsigned short u16x4 __attribute__((ext_vector_type(4)));
typedef unsigned short u16x8 __attribute__((ext_vector_type(8)));
typedef __bf16 bf16x8 __attribute__((ext_vector_type(8)));

// ---------- helpers ----------
__device__ __forceinline__ unsigned short f2bf(float f) {
  unsigned u = __float_as_uint(f);
  u += 0x7fffu + ((u >> 16) & 1u);   // RNE; inputs finite
  return (unsigned short)(u >> 16);
}
__device__ __forceinline__ float bf2f(unsigned short h) {
  return __uint_as_float(((unsigned)h) << 16);
}
__device__ __forceinline__ f32x4 mfma16x16x32(u16x8 a, u16x8 b, f32x4 c) {
  return __builtin_amdgcn_mfma_f32_16x16x32_bf16(
      __builtin_bit_cast(bf16x8, a), __builtin_bit_cast(bf16x8, b), c, 0, 0, 0);
}
__device__ __forceinline__ void gload_lds16(const unsigned short* g, unsigned short* l) {
  __builtin_amdgcn_global_load_lds((__attribute__((address_space(1))) void*)(g),
                                   (__attribute__((address_space(3))) void*)(l), 16, 0, 0);
}

// ---------- weight fp32 -> bf16 cast ----------
__global__ __launch_bounds__(256)
void cvt_weights(const float* __restrict__ wq, const float* __restrict__ wo,
                 const float* __restrict__ w1, const float* __restrict__ w2,
                 unsigned short* __restrict__ dst) {
  int i4 = blockIdx.x * 256 + threadIdx.x;
  int e = i4 << 2;
  const float* src; int off;
  if (e < 786432)       { src = wq; off = 0; }
  else if (e < 1048576) { src = wo; off = 786432; }
  else if (e < 2097152) { src = w1; off = 1048576; }
  else                  { src = w2; off = 2097152; }
  int le = e - off;
  f32x4 v = *(const f32x4*)(src + le);
  u16x4 o;
  #pragma unroll
  for (int i = 0; i < 4; ++i) o[i] = f2bf(v[i]);
  *(u16x4*)(dst + e) = o;
}

// ---------- LayerNorm (fp32 in) -> bf16 out ----------
__global__ __launch_bounds__(256)
void ln_bf16(const float* __restrict__ x, const float* __restrict__ w,
             const float* __restrict__ b, unsigned short* __restrict__ out) {
  const int row = (blockIdx.x << 2) + (threadIdx.x >> 6);
  const int lane = threadIdx.x & 63;
  const float* xr = x + (size_t)row * 512 + (lane << 3);
  f32x4 v0 = *(const f32x4*)xr;
  f32x4 v1 = *(const f32x4*)(xr + 4);
  float s = 0.f, s2 = 0.f;
  #pragma unroll
  for (int i = 0; i < 4; ++i) { s += v0[i] + v1[i]; s2 += v0[i]*v0[i] + v1[i]*v1[i]; }
  #pragma unroll
  for (int m = 1; m < 64; m <<= 1) { s += __shfl_xor(s, m); s2 += __shfl_xor(s2, m); }
  float mean = s * (1.0f / 512.0f);
  float var  = s2 * (1.0f / 512.0f) - mean * mean;
  float rs = rsqrtf(var + 1e-5f);
  const int d = lane << 3;
  u16x8 o;
  #pragma unroll
  for (int i = 0; i < 8; ++i) {
    float xv = (i < 4) ? v0[i] : v1[i - 4];
    o[i] = f2bf((xv - mean) * rs * w[d + i] + b[d + i]);
  }
  *(u16x8*)(out + (size_t)row * 512 + d) = o;
}

// ---------- GEMM: C[M,N] = A[M,K](bf16,rm) * B[N,K](bf16,rm)^T + epilogue ----------
// Double-buffered LDS, ONE __syncthreads per K-step (T3 minimum-pipeline):
// prologue stage(buf0); loop { sync(drains vmcnt); stage(next); compute(cur) }.
// EPI 0: +bias -> bf16   EPI 1: +bias+resid -> fp32   EPI 2: +bias, GELU -> bf16
template<int BM, int BN, int EPI>
__global__ __launch_bounds__(256)
void gemm_bt(const unsigned short* __restrict__ A, const unsigned short* __restrict__ B,
             const float* __restrict__ bias, const float* __restrict__ resid,
             float* __restrict__ Cf, unsigned short* __restrict__ Cb,
             int M, int N, int K) {
  constexpr int AM = BM / 32, AN = BN / 32;     // per-wave 16x16 frags
  __shared__ __align__(16) unsigned short lA[2][BM * 64];
  __shared__ __align__(16) unsigned short lB[2][BN * 64];
  const int tid = threadIdx.x;
  const int wave = tid >> 6, lane = tid & 63;
  const int gn = N / BN;
  const int tm = blockIdx.x / gn, tn = blockIdx.x - tm * gn;
  const int m0 = tm * BM, n0 = tn * BN;
  const int wr = wave >> 1, wc = wave & 1;
  const int lr = lane & 15;
  const int lk = (lane >> 4) << 3;
  const int srow = tid >> 3;             // 0..31 staging row within 32-row chunk
  const int scol = (tid & 7) << 3;       // k-offset (8 bf16 = 16B)

  auto stage = [&](int buf, int k0) {
    #pragma unroll
    for (int it = 0; it < BM / 32; ++it)
      gload_lds16(A + (size_t)(m0 + (it << 5) + srow) * K + k0 + scol,
                  &lA[buf][((it << 8) + (wave << 6)) << 3]);
    #pragma unroll
    for (int it = 0; it < BN / 32; ++it)
      gload_lds16(B + (size_t)(n0 + (it << 5) + srow) * K + k0 + scol,
                  &lB[buf][((it << 8) + (wave << 6)) << 3]);
  };

  f32x4 acc[AM][AN] = {};
  const int NT = K >> 6;
  stage(0, 0);
  int cur = 0;
  for (int t = 0; t < NT; ++t) {
    __syncthreads();                      // drains own vmcnt + lgkm, then barrier
    if (t + 1 < NT) stage(cur ^ 1, (t + 1) << 6);
    #pragma unroll
    for (int kk = 0; kk < 64; kk += 32) {
      u16x8 af[AM], bfv[AN];
      #pragma unroll
      for (int m = 0; m < AM; ++m)
        af[m] = *(const u16x8*)&lA[cur][(wr * (BM / 2) + (m << 4) + lr) * 64 + kk + lk];
      #pragma unroll
      for (int n = 0; n < AN; ++n)
        bfv[n] = *(const u16x8*)&lB[cur][(wc * (BN / 2) + (n << 4) + lr) * 64 + kk + lk];
      #pragma unroll
      for (int m = 0; m < AM; ++m)
        #pragma unroll
        for (int n = 0; n < AN; ++n)
          acc[m][n] = mfma16x16x32(af[m], bfv[n], acc[m][n]);
    }
    cur ^= 1;
  }
  const int rbase = m0 + wr * (BM / 2) + ((lane >> 4) << 2);
  const int cbase = n0 + wc * (BN / 2) + lr;
  #pragma unroll
  for (int m = 0; m < AM; ++m) {
    #pragma unroll
    for (int n = 0; n < AN; ++n) {
      int col = cbase + (n << 4);
      float bcol = bias[col];
      #pragma unroll
      for (int i = 0; i < 4; ++i) {
        int row = rbase + (m << 4) + i;
        float v = acc[m][n][i] + bcol;
        size_t off = (size_t)row * N + col;
        if (EPI == 0) {
          Cb[off] = f2bf(v);
        } else if (EPI == 1) {
          Cf[off] = v + resid[off];
        } else {
          float g = 0.5f * v * (1.0f + erff(v * 0.70710678f));
          Cb[off] = f2bf(g);
        }
      }
    }
  }
}

// ---------- MFMA dilated windowed causal attention ----------
// DIL=2: two independent causal 129-key sliding-window attentions over the
// even/odd subsequences (len 1024). Block = (b,h,par, 64-query span); 4 waves,
// each wave owns a 16-query tile attending to 144 keys (9 QK tiles, 5 PV
// k-steps with K-dim padded to 160; P pad cols and Vt pad rows are zeroed).
__global__ __launch_bounds__(256)
void attn_mfma(const unsigned short* __restrict__ qkv, unsigned short* __restrict__ out) {
  __shared__ __align__(16) unsigned short Vt[64 * 216];      // V^T: [d][k], ld=216
  __shared__ __align__(16) unsigned short Pl[4][16 * 168];   // per-wave P: [q][k], ld=168
  const int bid = blockIdx.x;
  const int qt  = bid & 15;
  const int par = (bid >> 4) & 1;
  const int h   = (bid >> 5) & 7;
  const int b   = bid >> 8;
  const int q0  = qt << 6;
  const int tid = threadIdx.x, wave = tid >> 6, lane = tid & 63;

  for (int c = tid; c < 208 * 16; c += 256) {
    int r = c >> 4, dc = (c & 15) << 2;
    int kp = q0 - 128 + r;
    u16x4 vb = {0, 0, 0, 0};
    if (r < 192 && kp >= 0) {
      size_t base = ((size_t)((b << 11) + (kp << 1) + par)) * 1536 + 1024 + (h << 6) + dc;
      vb = *(const u16x4*)(qkv + base);
    }
    #pragma unroll
    for (int e = 0; e < 4; ++e) Vt[(dc + e) * 216 + r] = vb[e];
  }
  __syncthreads();

  const int col = lane & 15;
  const int rg  = lane >> 4;
  const int qt0 = q0 + (wave << 4);
  unsigned short* Pw = Pl[wave];

  const long long qrow = (long long)((b << 11) + ((qt0 + col) << 1) + par);
  const unsigned short* qp = qkv + qrow * 1536 + (h << 6) + (rg << 3);
  u16x8 qa0 = *(const u16x8*)(qp);
  u16x8 qa1 = *(const u16x8*)(qp + 32);

  f32x4 sc[9];
  #pragma unroll
  for (int j = 0; j < 9; ++j) sc[j] = (f32x4){0.f, 0.f, 0.f, 0.f};
  #pragma unroll
  for (int j = 0; j < 9; ++j) {
    int kpj = qt0 - 128 + (j << 4) + col;
    long long krow = (long long)((b << 11) + (kpj << 1) + par);
    const unsigned short* kp = qkv + krow * 1536 + 512 + (h << 6) + (rg << 3);
    u16x8 k0 = *(const u16x8*)(kp);
    u16x8 k1 = *(const u16x8*)(kp + 32);
    sc[j] = mfma16x16x32(qa0, k0, sc[j]);
    sc[j] = mfma16x16x32(qa1, k1, sc[j]);
  }

  float mrow[4] = {-3e38f, -3e38f, -3e38f, -3e38f};
  #pragma unroll
  for (int j = 0; j < 9; ++j) {
    #pragma unroll
    for (int i = 0; i < 4; ++i) {
      int qr = (rg << 2) + i;
      int jk = (j << 4) + col;
      bool ok = (jk >= qr) && (jk <= qr + 128) && (qt0 + jk >= 128);
      float s = ok ? sc[j][i] * 0.125f : -1e30f;
      sc[j][i] = s;
      mrow[i] = fmaxf(mrow[i], s);
    }
  }
  #pragma unroll
  for (int i = 0; i < 4; ++i)
    #pragma unroll
    for (int m = 1; m < 16; m <<= 1) mrow[i] = fmaxf(mrow[i], __shfl_xor(mrow[i], m));

  float lrow[4] = {0.f, 0.f, 0.f, 0.f};
  #pragma unroll
  for (int j = 0; j < 9; ++j) {
    #pragma unroll
    for (int i = 0; i < 4; ++i) {
      float p = __expf(sc[j][i] - mrow[i]);
      lrow[i] += p;
      Pw[((rg << 2) + i) * 168 + (j << 4) + col] = f2bf(p);
    }
  }
  #pragma unroll
  for (int i = 0; i < 4; ++i)
    Pw[((rg << 2) + i) * 168 + 144 + col] = 0;
  #pragma unroll
  for (int i = 0; i < 4; ++i)
    #pragma unroll
    for (int m = 1; m < 16; m <<= 1) lrow[i] += __shfl_xor(lrow[i], m);
  float inv[4];
  #pragma unroll
  for (int i = 0; i < 4; ++i) inv[i] = 1.0f / lrow[i];

  f32x4 oacc[4] = {};
  #pragma unroll
  for (int ks = 0; ks < 5; ++ks) {
    int kk = ks << 5;
    u16x8 pa = *(const u16x8*)&Pw[col * 168 + kk + (rg << 3)];
    #pragma unroll
    for (int n = 0; n < 4; ++n) {
      u16x8 vb = *(const u16x8*)&Vt[((n << 4) + col) * 216 + (wave << 4) + kk + (rg << 3)];
      oacc[n] = mfma16x16x32(pa, vb, oacc[n]);
    }
  }

  #pragma unroll
  for (int n = 0; n < 4; ++n) {
    #pragma unroll
    for (int i = 0; i < 4; ++i) {
      int q = qt0 + (rg << 2) + i;
      size_t off = ((size_t)((b << 11) + (q << 1) + par)) * 512 + (h << 6) + (n << 4) + col;
      out[off] = f2bf(oacc[n][i] * inv[i]);
    }
  }
}

// ---------- launch ----------
extern "C" void kernel_launch(void* const* d_in, const int* in_sizes, int n_in,
                              void* d_out, int out_size, void* d_ws, size_t ws_size,
                              hipStream_t stream) {
  const float* x     = (const float*)d_in[0];
  const float* n1w   = (const float*)d_in[1];
  const float* n1b   = (const float*)d_in[2];
  const float* qkv_w = (const float*)d_in[3];
  const float* qkv_b = (const float*)d_in[4];
  const float* out_w = (const float*)d_in[5];
  const float* out_b = (const float*)d_in[6];
  const float* n2w   = (const float*)d_in[7];
  const float* n2b   = (const float*)d_in[8];
  const float* w1    = (const float*)d_in[9];
  const float* b1    = (const float*)d_in[10];
  const float* w2    = (const float*)d_in[11];
  const float* b2    = (const float*)d_in[12];

  char* ws = (char*)d_ws;
  unsigned short* wbf   = (unsigned short*)(ws);
  unsigned short* wq_bf = wbf;                              // [1536,512]
  unsigned short* wo_bf = (unsigned short*)(ws + 1572864);  // [512,512]
  unsigned short* w1_bf = (unsigned short*)(ws + 2097152);  // [2048,512]
  unsigned short* w2_bf = (unsigned short*)(ws + 4194304);  // [512,2048]
  unsigned short* h_bf  = (unsigned short*)(ws + 6291456);  // [4096,512]
  unsigned short* qkvb  = (unsigned short*)(ws + 10485760); // [4096,1536] bf16
  unsigned short* ao_bf = (unsigned short*)(ws + 23068672); // [4096,512] bf16
  float*          x1    = (float*)(ws + 27262976);          // [4096,512] fp32
  unsigned short* f1_bf = (unsigned short*)(ws + 10485760); // [4096,2048] aliases dead qkv+ao
  float* outp = (float*)d_out;

  cvt_weights<<<3072, 256, 0, stream>>>(qkv_w, out_w, w1, w2, wbf);
  ln_bf16<<<1024, 256, 0, stream>>>(x, n1w, n1b, h_bf);
  gemm_bt<128, 64, 0><<<32 * 24, 256, 0, stream>>>(h_bf, wq_bf, qkv_b, nullptr,
                                                   nullptr, qkvb, 4096, 1536, 512);
  attn_mfma<<<512, 256, 0, stream>>>(qkvb, ao_bf);
  gemm_bt<64, 64, 1><<<64 * 8, 256, 0, stream>>>(ao_bf, wo_bf, out_b, x, x1,
                                                 nullptr, 4096, 512, 512);
  ln_bf16<<<1024, 256, 0, stream>>>(x1, n2w, n2b, h_bf);
  gemm_bt<128, 64, 2><<<32 * 32, 256, 0, stream>>>(h_bf, w1_bf, b1, nullptr,
                                                   nullptr, f1_bf, 4096, 2048, 512);
  gemm_bt<64, 64, 1><<<64 * 8, 256, 0, stream>>>(f1_bf, w2_bf, b2, x1, outp,
                                                 nullptr, 4096, 512, 2048);
}

// Round 5
// 103.906 us; speedup vs baseline: 1.0683x; 1.0683x over previous
//
#include <hip/hip_runtime.h>
#include <stdint.h>

typedef float f32x4 __attribute__((ext_vector_type(4)));
typedef unsigned short u16x4 __attribute__((ext_vector_type(4)));
typedef unsigned short u16x8 __attribute__((ext_vector_type(8)));
typedef __bf16 bf16x8 __attribute__((ext_vector_type(8)));

// ---------- helpers ----------
__device__ __forceinline__ unsigned short f2bf(float f) {
  unsigned u = __float_as_uint(f);
  u += 0x7fffu + ((u >> 16) & 1u);   // RNE; inputs finite
  return (unsigned short)(u >> 16);
}
__device__ __forceinline__ float bf2f(unsigned short h) {
  return __uint_as_float(((unsigned)h) << 16);
}
__device__ __forceinline__ f32x4 mfma16x16x32(u16x8 a, u16x8 b, f32x4 c) {
  return __builtin_amdgcn_mfma_f32_16x16x32_bf16(
      __builtin_bit_cast(bf16x8, a), __builtin_bit_cast(bf16x8, b), c, 0, 0, 0);
}
__device__ __forceinline__ void gload_lds16(const unsigned short* g, unsigned short* l) {
  __builtin_amdgcn_global_load_lds((__attribute__((address_space(1))) void*)(g),
                                   (__attribute__((address_space(3))) void*)(l), 16, 0, 0);
}

// ---------- fused: weight fp32->bf16 cast (blocks 0..3071) + LayerNorm1 (3072..4095) ----------
__global__ __launch_bounds__(256)
void prep(const float* __restrict__ wq, const float* __restrict__ wo,
          const float* __restrict__ w1, const float* __restrict__ w2,
          unsigned short* __restrict__ dst,
          const float* __restrict__ x, const float* __restrict__ nw,
          const float* __restrict__ nb, unsigned short* __restrict__ hout) {
  if (blockIdx.x < 3072) {
    int i4 = blockIdx.x * 256 + threadIdx.x;
    int e = i4 << 2;
    const float* src; int off;
    if (e < 786432)       { src = wq; off = 0; }
    else if (e < 1048576) { src = wo; off = 786432; }
    else if (e < 2097152) { src = w1; off = 1048576; }
    else                  { src = w2; off = 2097152; }
    int le = e - off;
    f32x4 v = *(const f32x4*)(src + le);
    u16x4 o;
    #pragma unroll
    for (int i = 0; i < 4; ++i) o[i] = f2bf(v[i]);
    *(u16x4*)(dst + e) = o;
  } else {
    const int row = ((blockIdx.x - 3072) << 2) + (threadIdx.x >> 6);
    const int lane = threadIdx.x & 63;
    const float* xr = x + (size_t)row * 512 + (lane << 3);
    f32x4 v0 = *(const f32x4*)xr;
    f32x4 v1 = *(const f32x4*)(xr + 4);
    float s = 0.f, s2 = 0.f;
    #pragma unroll
    for (int i = 0; i < 4; ++i) { s += v0[i] + v1[i]; s2 += v0[i]*v0[i] + v1[i]*v1[i]; }
    #pragma unroll
    for (int m = 1; m < 64; m <<= 1) { s += __shfl_xor(s, m); s2 += __shfl_xor(s2, m); }
    float mean = s * (1.0f / 512.0f);
    float var  = s2 * (1.0f / 512.0f) - mean * mean;
    float rs = rsqrtf(var + 1e-5f);
    const int d = lane << 3;
    u16x8 o;
    #pragma unroll
    for (int i = 0; i < 8; ++i) {
      float xv = (i < 4) ? v0[i] : v1[i - 4];
      o[i] = f2bf((xv - mean) * rs * nw[d + i] + nb[d + i]);
    }
    *(u16x8*)(hout + (size_t)row * 512 + d) = o;
  }
}

// ---------- LayerNorm (fp32 in) -> bf16 out ----------
__global__ __launch_bounds__(256)
void ln_bf16(const float* __restrict__ x, const float* __restrict__ w,
             const float* __restrict__ b, unsigned short* __restrict__ out) {
  const int row = (blockIdx.x << 2) + (threadIdx.x >> 6);
  const int lane = threadIdx.x & 63;
  const float* xr = x + (size_t)row * 512 + (lane << 3);
  f32x4 v0 = *(const f32x4*)xr;
  f32x4 v1 = *(const f32x4*)(xr + 4);
  float s = 0.f, s2 = 0.f;
  #pragma unroll
  for (int i = 0; i < 4; ++i) { s += v0[i] + v1[i]; s2 += v0[i]*v0[i] + v1[i]*v1[i]; }
  #pragma unroll
  for (int m = 1; m < 64; m <<= 1) { s += __shfl_xor(s, m); s2 += __shfl_xor(s2, m); }
  float mean = s * (1.0f / 512.0f);
  float var  = s2 * (1.0f / 512.0f) - mean * mean;
  float rs = rsqrtf(var + 1e-5f);
  const int d = lane << 3;
  u16x8 o;
  #pragma unroll
  for (int i = 0; i < 8; ++i) {
    float xv = (i < 4) ? v0[i] : v1[i - 4];
    o[i] = f2bf((xv - mean) * rs * w[d + i] + b[d + i]);
  }
  *(u16x8*)(out + (size_t)row * 512 + d) = o;
}

// ---------- GEMM: C[M,N] = A[M,K](bf16,rm) * B[N,K](bf16,rm)^T + epilogue ----------
// Single-buffer LDS (round-3 structure; dbuf measured NEGATIVE at this occupancy).
// EPI 0: +bias -> bf16   EPI 1: +bias+resid -> fp32   EPI 2: +bias, GELU -> bf16
// WRV: additionally scatter-write cols>=1024 (the V third) transposed into
// vt[b][par][h][d][k'] for the attention kernel's vectorized V^T reads.
template<int BM, int BN, int EPI, int WRV>
__global__ __launch_bounds__(256)
void gemm_bt(const unsigned short* __restrict__ A, const unsigned short* __restrict__ B,
             const float* __restrict__ bias, const float* __restrict__ resid,
             float* __restrict__ Cf, unsigned short* __restrict__ Cb,
             unsigned short* __restrict__ vt,
             int M, int N, int K) {
  constexpr int AM = BM / 32, AN = BN / 32;     // per-wave 16x16 frags
  __shared__ __align__(16) unsigned short lA[BM * 64];
  __shared__ __align__(16) unsigned short lB[BN * 64];
  const int tid = threadIdx.x;
  const int wave = tid >> 6, lane = tid & 63;
  const int gn = N / BN;
  const int tm = blockIdx.x / gn, tn = blockIdx.x - tm * gn;
  const int m0 = tm * BM, n0 = tn * BN;
  const int wr = wave >> 1, wc = wave & 1;
  const int lr = lane & 15;
  const int lk = (lane >> 4) << 3;
  const int srow = tid >> 3;             // 0..31 staging row within 32-row chunk
  const int scol = (tid & 7) << 3;       // k-offset (8 bf16 = 16B)
  f32x4 acc[AM][AN] = {};
  for (int k0 = 0; k0 < K; k0 += 64) {
    #pragma unroll
    for (int it = 0; it < BM / 32; ++it)
      gload_lds16(A + (size_t)(m0 + (it << 5) + srow) * K + k0 + scol,
                  &lA[((it << 8) + (wave << 6)) << 3]);
    #pragma unroll
    for (int it = 0; it < BN / 32; ++it)
      gload_lds16(B + (size_t)(n0 + (it << 5) + srow) * K + k0 + scol,
                  &lB[((it << 8) + (wave << 6)) << 3]);
    __syncthreads();
    #pragma unroll
    for (int kk = 0; kk < 64; kk += 32) {
      u16x8 af[AM], bfv[AN];
      #pragma unroll
      for (int m = 0; m < AM; ++m)
        af[m] = *(const u16x8*)&lA[(wr * (BM / 2) + (m << 4) + lr) * 64 + kk + lk];
      #pragma unroll
      for (int n = 0; n < AN; ++n)
        bfv[n] = *(const u16x8*)&lB[(wc * (BN / 2) + (n << 4) + lr) * 64 + kk + lk];
      #pragma unroll
      for (int m = 0; m < AM; ++m)
        #pragma unroll
        for (int n = 0; n < AN; ++n)
          acc[m][n] = mfma16x16x32(af[m], bfv[n], acc[m][n]);
    }
    __syncthreads();
  }
  const int rbase = m0 + wr * (BM / 2) + ((lane >> 4) << 2);
  const int cbase = n0 + wc * (BN / 2) + lr;
  #pragma unroll
  for (int m = 0; m < AM; ++m) {
    #pragma unroll
    for (int n = 0; n < AN; ++n) {
      int col = cbase + (n << 4);
      float bcol = bias[col];
      #pragma unroll
      for (int i = 0; i < 4; ++i) {
        int row = rbase + (m << 4) + i;
        float v = acc[m][n][i] + bcol;
        size_t off = (size_t)row * N + col;
        if (EPI == 0) {
          Cb[off] = f2bf(v);
        } else if (EPI == 1) {
          Cf[off] = v + resid[off];
        } else {
          float g = 0.5f * v * (1.0f + erff(v * 0.70710678f));
          Cb[off] = f2bf(g);
        }
        if (WRV && col >= 1024) {   // V third -> transposed vt[b][par][h][d][k']
          int hh = (col - 1024) >> 6, dd = (col - 1024) & 63;
          int bb = row >> 11, tok = row & 2047;
          long long vrow = ((((((long long)bb << 1) + (tok & 1)) << 3) + hh) << 6) + dd;
          vt[(vrow << 10) + (tok >> 1)] = f2bf(v);
        }
      }
    }
  }
}

// ---------- MFMA dilated windowed causal attention (barrier-free) ----------
// DIL=2: two independent causal 129-key sliding-window attentions over the
// even/odd subsequences (len 1024). Block = (b,h,par, 64-query span); 4
// independent waves, each owning a 16-query tile attending to 144 keys
// (9 QK tiles; PV K-dim padded to 160, pad P cols zeroed). Q/K direct from
// global; V^T fragments are contiguous vector loads from the vt buffer
// written by the QKV GEMM epilogue. P roundtrips through wave-local LDS.
__global__ __launch_bounds__(256)
void attn_mfma(const unsigned short* __restrict__ qkv,
               const unsigned short* __restrict__ vt,
               unsigned short* __restrict__ out) {
  __shared__ __align__(16) unsigned short Pl[4][16 * 168];   // per-wave P: [q][k], ld=168
  const int bid = blockIdx.x;
  const int qt  = bid & 15;
  const int par = (bid >> 4) & 1;
  const int h   = (bid >> 5) & 7;
  const int b   = bid >> 8;
  const int q0  = qt << 6;
  const int tid = threadIdx.x, wave = tid >> 6, lane = tid & 63;

  const int col = lane & 15;
  const int rg  = lane >> 4;
  const int qt0 = q0 + (wave << 4);
  unsigned short* Pw = Pl[wave];

  // Q a-fragments direct from global
  const long long qrow = (long long)((b << 11) + ((qt0 + col) << 1) + par);
  const unsigned short* qp = qkv + qrow * 1536 + (h << 6) + (rg << 3);
  u16x8 qa0 = *(const u16x8*)(qp);
  u16x8 qa1 = *(const u16x8*)(qp + 32);

  // QK^T: 9 key sub-tiles, K b-frags direct from global (kp<0 reads earlier
  // ws regions -> finite garbage, masked below)
  f32x4 sc[9];
  #pragma unroll
  for (int j = 0; j < 9; ++j) sc[j] = (f32x4){0.f, 0.f, 0.f, 0.f};
  #pragma unroll
  for (int j = 0; j < 9; ++j) {
    int kpj = qt0 - 128 + (j << 4) + col;
    long long krow = (long long)((b << 11) + (kpj << 1) + par);
    const unsigned short* kp = qkv + krow * 1536 + 512 + (h << 6) + (rg << 3);
    u16x8 k0 = *(const u16x8*)(kp);
    u16x8 k1 = *(const u16x8*)(kp + 32);
    sc[j] = mfma16x16x32(qa0, k0, sc[j]);
    sc[j] = mfma16x16x32(qa1, k1, sc[j]);
  }

  // mask + scale + row max (rows in (rg,i); cols in lane bits 0-3)
  float mrow[4] = {-3e38f, -3e38f, -3e38f, -3e38f};
  #pragma unroll
  for (int j = 0; j < 9; ++j) {
    #pragma unroll
    for (int i = 0; i < 4; ++i) {
      int qr = (rg << 2) + i;
      int jk = (j << 4) + col;
      bool ok = (jk >= qr) && (jk <= qr + 128) && (qt0 + jk >= 128);
      float s = ok ? sc[j][i] * 0.125f : -1e30f;
      sc[j][i] = s;
      mrow[i] = fmaxf(mrow[i], s);
    }
  }
  #pragma unroll
  for (int i = 0; i < 4; ++i)
    #pragma unroll
    for (int m = 1; m < 16; m <<= 1) mrow[i] = fmaxf(mrow[i], __shfl_xor(mrow[i], m));

  // exp, row sum, write P (bf16) to wave-local LDS
  float lrow[4] = {0.f, 0.f, 0.f, 0.f};
  #pragma unroll
  for (int j = 0; j < 9; ++j) {
    #pragma unroll
    for (int i = 0; i < 4; ++i) {
      float p = __expf(sc[j][i] - mrow[i]);
      lrow[i] += p;
      Pw[((rg << 2) + i) * 168 + (j << 4) + col] = f2bf(p);
    }
  }
  #pragma unroll
  for (int i = 0; i < 4; ++i)
    Pw[((rg << 2) + i) * 168 + 144 + col] = 0;   // zero pad cols 144..159
  #pragma unroll
  for (int i = 0; i < 4; ++i)
    #pragma unroll
    for (int m = 1; m < 16; m <<= 1) lrow[i] += __shfl_xor(lrow[i], m);
  float inv[4];
  #pragma unroll
  for (int i = 0; i < 4; ++i) inv[i] = 1.0f / lrow[i];

  // PV: O[16x64] = P[16x160] * Vt^T ; Vt b-frags are contiguous u16x8 global loads
  const long long vbase = ((long long)((((b << 1) + par) << 3) + h)) << 16;  // *64*1024
  f32x4 oacc[4] = {};
  #pragma unroll
  for (int ks = 0; ks < 5; ++ks) {
    int kk = ks << 5;
    u16x8 pa = *(const u16x8*)&Pw[col * 168 + kk + (rg << 3)];
    long long kp0 = (long long)qt0 - 128 + kk + (rg << 3);   // may be negative
    #pragma unroll
    for (int n = 0; n < 4; ++n) {
      const unsigned short* vp = vt + vbase + (((long long)((n << 4) + col)) << 10) + kp0;
      u16x8 vb = *(const u16x8*)(vp);
      oacc[n] = mfma16x16x32(pa, vb, oacc[n]);
    }
  }

  // epilogue: normalize, store bf16
  #pragma unroll
  for (int n = 0; n < 4; ++n) {
    #pragma unroll
    for (int i = 0; i < 4; ++i) {
      int q = qt0 + (rg << 2) + i;
      size_t off = ((size_t)((b << 11) + (q << 1) + par)) * 512 + (h << 6) + (n << 4) + col;
      out[off] = f2bf(oacc[n][i] * inv[i]);
    }
  }
}

// ---------- launch ----------
extern "C" void kernel_launch(void* const* d_in, const int* in_sizes, int n_in,
                              void* d_out, int out_size, void* d_ws, size_t ws_size,
                              hipStream_t stream) {
  const float* x     = (const float*)d_in[0];
  const float* n1w   = (const float*)d_in[1];
  const float* n1b   = (const float*)d_in[2];
  const float* qkv_w = (const float*)d_in[3];
  const float* qkv_b = (const float*)d_in[4];
  const float* out_w = (const float*)d_in[5];
  const float* out_b = (const float*)d_in[6];
  const float* n2w   = (const float*)d_in[7];
  const float* n2b   = (const float*)d_in[8];
  const float* w1    = (const float*)d_in[9];
  const float* b1    = (const float*)d_in[10];
  const float* w2    = (const float*)d_in[11];
  const float* b2    = (const float*)d_in[12];

  char* ws = (char*)d_ws;
  unsigned short* wbf   = (unsigned short*)(ws);
  unsigned short* wq_bf = wbf;                              // [1536,512]
  unsigned short* wo_bf = (unsigned short*)(ws + 1572864);  // [512,512]
  unsigned short* w1_bf = (unsigned short*)(ws + 2097152);  // [2048,512]
  unsigned short* w2_bf = (unsigned short*)(ws + 4194304);  // [512,2048]
  unsigned short* h_bf  = (unsigned short*)(ws + 6291456);  // [4096,512]
  unsigned short* qkvb  = (unsigned short*)(ws + 10485760); // [4096,1536] bf16
  unsigned short* ao_bf = (unsigned short*)(ws + 23068672); // [4096,512] bf16
  float*          x1    = (float*)(ws + 27262976);          // [4096,512] fp32
  unsigned short* f1_bf = (unsigned short*)(ws + 10485760); // [4096,2048] aliases dead qkv+ao
  unsigned short* vt    = (unsigned short*)(ws + 35651584); // [2,2,8,64,1024] V^T bf16, 4MB
  float* outp = (float*)d_out;

  prep<<<4096, 256, 0, stream>>>(qkv_w, out_w, w1, w2, wbf, x, n1w, n1b, h_bf);
  gemm_bt<128, 64, 0, 1><<<32 * 24, 256, 0, stream>>>(h_bf, wq_bf, qkv_b, nullptr,
                                                      nullptr, qkvb, vt, 4096, 1536, 512);
  attn_mfma<<<512, 256, 0, stream>>>(qkvb, vt, ao_bf);
  gemm_bt<64, 64, 1, 0><<<64 * 8, 256, 0, stream>>>(ao_bf, wo_bf, out_b, x, x1,
                                                    nullptr, nullptr, 4096, 512, 512);
  ln_bf16<<<1024, 256, 0, stream>>>(x1, n2w, n2b, h_bf);
  gemm_bt<128, 64, 2, 0><<<32 * 32, 256, 0, stream>>>(h_bf, w1_bf, b1, nullptr,
                                                      nullptr, f1_bf, nullptr, 4096, 2048, 512);
  gemm_bt<64, 64, 1, 0><<<64 * 8, 256, 0, stream>>>(f1_bf, w2_bf, b2, x1, outp,
                                                    nullptr, nullptr, 4096, 512, 2048);
}

// Round 6
// 94.925 us; speedup vs baseline: 1.1694x; 1.0946x over previous
//
#include <hip/hip_runtime.h>
#include <stdint.h>

typedef float f32x4 __attribute__((ext_vector_type(4)));
typedef unsigned short u16x4 __attribute__((ext_vector_type(4)));
typedef unsigned short u16x8 __attribute__((ext_vector_type(8)));
typedef __bf16 bf16x8 __attribute__((ext_vector_type(8)));

// ---------- helpers ----------
__device__ __forceinline__ unsigned short f2bf(float f) {
  unsigned u = __float_as_uint(f);
  u += 0x7fffu + ((u >> 16) & 1u);   // RNE; inputs finite
  return (unsigned short)(u >> 16);
}
__device__ __forceinline__ float bf2f(unsigned short h) {
  return __uint_as_float(((unsigned)h) << 16);
}
__device__ __forceinline__ f32x4 mfma16x16x32(u16x8 a, u16x8 b, f32x4 c) {
  return __builtin_amdgcn_mfma_f32_16x16x32_bf16(
      __builtin_bit_cast(bf16x8, a), __builtin_bit_cast(bf16x8, b), c, 0, 0, 0);
}
__device__ __forceinline__ void gload_lds16(const unsigned short* g, unsigned short* l) {
  __builtin_amdgcn_global_load_lds((__attribute__((address_space(1))) void*)(g),
                                   (__attribute__((address_space(3))) void*)(l), 16, 0, 0);
}

// ---------- fused: weight fp32->bf16 cast (blocks 0..3071) + LayerNorm1 (3072..4095) ----------
__global__ __launch_bounds__(256)
void prep(const float* __restrict__ wq, const float* __restrict__ wo,
          const float* __restrict__ w1, const float* __restrict__ w2,
          unsigned short* __restrict__ dst,
          const float* __restrict__ x, const float* __restrict__ nw,
          const float* __restrict__ nb, unsigned short* __restrict__ hout) {
  if (blockIdx.x < 3072) {
    int i4 = blockIdx.x * 256 + threadIdx.x;
    int e = i4 << 2;
    const float* src; int off;
    if (e < 786432)       { src = wq; off = 0; }
    else if (e < 1048576) { src = wo; off = 786432; }
    else if (e < 2097152) { src = w1; off = 1048576; }
    else                  { src = w2; off = 2097152; }
    int le = e - off;
    f32x4 v = *(const f32x4*)(src + le);
    u16x4 o;
    #pragma unroll
    for (int i = 0; i < 4; ++i) o[i] = f2bf(v[i]);
    *(u16x4*)(dst + e) = o;
  } else {
    const int row = ((blockIdx.x - 3072) << 2) + (threadIdx.x >> 6);
    const int lane = threadIdx.x & 63;
    const float* xr = x + (size_t)row * 512 + (lane << 3);
    f32x4 v0 = *(const f32x4*)xr;
    f32x4 v1 = *(const f32x4*)(xr + 4);
    float s = 0.f, s2 = 0.f;
    #pragma unroll
    for (int i = 0; i < 4; ++i) { s += v0[i] + v1[i]; s2 += v0[i]*v0[i] + v1[i]*v1[i]; }
    #pragma unroll
    for (int m = 1; m < 64; m <<= 1) { s += __shfl_xor(s, m); s2 += __shfl_xor(s2, m); }
    float mean = s * (1.0f / 512.0f);
    float var  = s2 * (1.0f / 512.0f) - mean * mean;
    float rs = rsqrtf(var + 1e-5f);
    const int d = lane << 3;
    u16x8 o;
    #pragma unroll
    for (int i = 0; i < 8; ++i) {
      float xv = (i < 4) ? v0[i] : v1[i - 4];
      o[i] = f2bf((xv - mean) * rs * nw[d + i] + nb[d + i]);
    }
    *(u16x8*)(hout + (size_t)row * 512 + d) = o;
  }
}

// ---------- LayerNorm (fp32 in) -> bf16 out ----------
__global__ __launch_bounds__(256)
void ln_bf16(const float* __restrict__ x, const float* __restrict__ w,
             const float* __restrict__ b, unsigned short* __restrict__ out) {
  const int row = (blockIdx.x << 2) + (threadIdx.x >> 6);
  const int lane = threadIdx.x & 63;
  const float* xr = x + (size_t)row * 512 + (lane << 3);
  f32x4 v0 = *(const f32x4*)xr;
  f32x4 v1 = *(const f32x4*)(xr + 4);
  float s = 0.f, s2 = 0.f;
  #pragma unroll
  for (int i = 0; i < 4; ++i) { s += v0[i] + v1[i]; s2 += v0[i]*v0[i] + v1[i]*v1[i]; }
  #pragma unroll
  for (int m = 1; m < 64; m <<= 1) { s += __shfl_xor(s, m); s2 += __shfl_xor(s2, m); }
  float mean = s * (1.0f / 512.0f);
  float var  = s2 * (1.0f / 512.0f) - mean * mean;
  float rs = rsqrtf(var + 1e-5f);
  const int d = lane << 3;
  u16x8 o;
  #pragma unroll
  for (int i = 0; i < 8; ++i) {
    float xv = (i < 4) ? v0[i] : v1[i - 4];
    o[i] = f2bf((xv - mean) * rs * w[d + i] + b[d + i]);
  }
  *(u16x8*)(out + (size_t)row * 512 + d) = o;
}

// ---------- GEMM: C[M,N] = A[M,K](bf16,rm) * B[N,K](bf16,rm)^T + epilogue ----------
// Single-buffer LDS, 2 barriers/K-step (dbuf measured negative at this occupancy).
// LDS XOR-swizzle (rule-21 compliant): linear LDS dest, inverse-permuted GLOBAL
// source chunk in stage(), same XOR on ds_read address -> bank-conflict-free.
// EPI 0: +bias -> bf16   EPI 1: +bias+resid -> fp32   EPI 2: +bias, GELU -> bf16
// WRV: scatter V third transposed into vt[b][par][h][d][k'] for attention.
template<int BM, int BN, int BK, int EPI, int WRV>
__global__ __launch_bounds__(256)
void gemm_bt(const unsigned short* __restrict__ A, const unsigned short* __restrict__ B,
             const float* __restrict__ bias, const float* __restrict__ resid,
             float* __restrict__ Cf, unsigned short* __restrict__ Cb,
             unsigned short* __restrict__ vt,
             int M, int N, int K) {
  constexpr int AM = BM / 32, AN = BN / 32;   // per-wave 16x16 frags
  constexpr int CPR = BK / 8;                 // 16B chunks per row
  constexpr int RPI = 2048 / BK;              // rows staged per 256-chunk block
  constexpr int LA = BM / RPI, LB = BN / RPI; // gloads per thread
  constexpr int XM = (CPR - 1) < 7 ? (CPR - 1) : 7;  // swizzle mask
  __shared__ __align__(16) unsigned short lA[BM * BK];
  __shared__ __align__(16) unsigned short lB[BN * BK];
  const int tid = threadIdx.x;
  const int wave = tid >> 6, lane = tid & 63;
  const int gn = N / BN;
  const int tm = blockIdx.x / gn, tn = blockIdx.x - tm * gn;
  const int m0 = tm * BM, n0 = tn * BN;
  const int wr = wave >> 1, wc = wave & 1;
  const int lr = lane & 15;
  const int lk = (lane >> 4) << 3;
  const int rit  = tid / CPR;                 // row within it-block
  const int csw  = ((tid % CPR) ^ (rit & XM)) << 3;  // swizzled source k-offset
  f32x4 acc[AM][AN] = {};
  for (int k0 = 0; k0 < K; k0 += BK) {
    #pragma unroll
    for (int it = 0; it < LA; ++it)
      gload_lds16(A + (size_t)(m0 + it * RPI + rit) * K + k0 + csw,
                  &lA[((it << 8) + (wave << 6)) << 3]);
    #pragma unroll
    for (int it = 0; it < LB; ++it)
      gload_lds16(B + (size_t)(n0 + it * RPI + rit) * K + k0 + csw,
                  &lB[((it << 8) + (wave << 6)) << 3]);
    __syncthreads();
    #pragma unroll
    for (int kk = 0; kk < BK; kk += 32) {
      u16x8 af[AM], bfv[AN];
      #pragma unroll
      for (int m = 0; m < AM; ++m) {
        int row = wr * (BM / 2) + (m << 4) + lr;
        int sc = ((((kk + lk) >> 3) ^ (lr & XM)) << 3);
        af[m] = *(const u16x8*)&lA[row * BK + sc];
      }
      #pragma unroll
      for (int n = 0; n < AN; ++n) {
        int row = wc * (BN / 2) + (n << 4) + lr;
        int sc = ((((kk + lk) >> 3) ^ (lr & XM)) << 3);
        bfv[n] = *(const u16x8*)&lB[row * BK + sc];
      }
      #pragma unroll
      for (int m = 0; m < AM; ++m)
        #pragma unroll
        for (int n = 0; n < AN; ++n)
          acc[m][n] = mfma16x16x32(af[m], bfv[n], acc[m][n]);
    }
    __syncthreads();
  }
  const int rbase = m0 + wr * (BM / 2) + ((lane >> 4) << 2);
  const int cbase = n0 + wc * (BN / 2) + lr;
  #pragma unroll
  for (int m = 0; m < AM; ++m) {
    #pragma unroll
    for (int n = 0; n < AN; ++n) {
      int col = cbase + (n << 4);
      float bcol = bias[col];
      #pragma unroll
      for (int i = 0; i < 4; ++i) {
        int row = rbase + (m << 4) + i;
        float v = acc[m][n][i] + bcol;
        size_t off = (size_t)row * N + col;
        if (EPI == 0) {
          Cb[off] = f2bf(v);
        } else if (EPI == 1) {
          Cf[off] = v + resid[off];
        } else {
          float g = 0.5f * v * (1.0f + erff(v * 0.70710678f));
          Cb[off] = f2bf(g);
        }
        if (WRV && col >= 1024) {   // V third -> transposed vt[b][par][h][d][k']
          int hh = (col - 1024) >> 6, dd = (col - 1024) & 63;
          int bb = row >> 11, tok = row & 2047;
          long long vrow = ((((((long long)bb << 1) + (tok & 1)) << 3) + hh) << 6) + dd;
          vt[(vrow << 10) + (tok >> 1)] = f2bf(v);
        }
      }
    }
  }
}

// ---------- MFMA dilated windowed causal attention (barrier-free) ----------
__global__ __launch_bounds__(256)
void attn_mfma(const unsigned short* __restrict__ qkv,
               const unsigned short* __restrict__ vt,
               unsigned short* __restrict__ out) {
  __shared__ __align__(16) unsigned short Pl[4][16 * 168];   // per-wave P: [q][k], ld=168
  const int bid = blockIdx.x;
  const int qt  = bid & 15;
  const int par = (bid >> 4) & 1;
  const int h   = (bid >> 5) & 7;
  const int b   = bid >> 8;
  const int q0  = qt << 6;
  const int tid = threadIdx.x, wave = tid >> 6, lane = tid & 63;

  const int col = lane & 15;
  const int rg  = lane >> 4;
  const int qt0 = q0 + (wave << 4);
  unsigned short* Pw = Pl[wave];

  const long long qrow = (long long)((b << 11) + ((qt0 + col) << 1) + par);
  const unsigned short* qp = qkv + qrow * 1536 + (h << 6) + (rg << 3);
  u16x8 qa0 = *(const u16x8*)(qp);
  u16x8 qa1 = *(const u16x8*)(qp + 32);

  f32x4 sc[9];
  #pragma unroll
  for (int j = 0; j < 9; ++j) sc[j] = (f32x4){0.f, 0.f, 0.f, 0.f};
  #pragma unroll
  for (int j = 0; j < 9; ++j) {
    int kpj = qt0 - 128 + (j << 4) + col;
    long long krow = (long long)((b << 11) + (kpj << 1) + par);
    const unsigned short* kp = qkv + krow * 1536 + 512 + (h << 6) + (rg << 3);
    u16x8 k0 = *(const u16x8*)(kp);
    u16x8 k1 = *(const u16x8*)(kp + 32);
    sc[j] = mfma16x16x32(qa0, k0, sc[j]);
    sc[j] = mfma16x16x32(qa1, k1, sc[j]);
  }

  float mrow[4] = {-3e38f, -3e38f, -3e38f, -3e38f};
  #pragma unroll
  for (int j = 0; j < 9; ++j) {
    #pragma unroll
    for (int i = 0; i < 4; ++i) {
      int qr = (rg << 2) + i;
      int jk = (j << 4) + col;
      bool ok = (jk >= qr) && (jk <= qr + 128) && (qt0 + jk >= 128);
      float s = ok ? sc[j][i] * 0.125f : -1e30f;
      sc[j][i] = s;
      mrow[i] = fmaxf(mrow[i], s);
    }
  }
  #pragma unroll
  for (int i = 0; i < 4; ++i)
    #pragma unroll
    for (int m = 1; m < 16; m <<= 1) mrow[i] = fmaxf(mrow[i], __shfl_xor(mrow[i], m));

  float lrow[4] = {0.f, 0.f, 0.f, 0.f};
  #pragma unroll
  for (int j = 0; j < 9; ++j) {
    #pragma unroll
    for (int i = 0; i < 4; ++i) {
      float p = __expf(sc[j][i] - mrow[i]);
      lrow[i] += p;
      Pw[((rg << 2) + i) * 168 + (j << 4) + col] = f2bf(p);
    }
  }
  #pragma unroll
  for (int i = 0; i < 4; ++i)
    Pw[((rg << 2) + i) * 168 + 144 + col] = 0;
  #pragma unroll
  for (int i = 0; i < 4; ++i)
    #pragma unroll
    for (int m = 1; m < 16; m <<= 1) lrow[i] += __shfl_xor(lrow[i], m);
  float inv[4];
  #pragma unroll
  for (int i = 0; i < 4; ++i) inv[i] = 1.0f / lrow[i];

  const long long vbase = ((long long)((((b << 1) + par) << 3) + h)) << 16;
  f32x4 oacc[4] = {};
  #pragma unroll
  for (int ks = 0; ks < 5; ++ks) {
    int kk = ks << 5;
    u16x8 pa = *(const u16x8*)&Pw[col * 168 + kk + (rg << 3)];
    long long kp0 = (long long)qt0 - 128 + kk + (rg << 3);
    #pragma unroll
    for (int n = 0; n < 4; ++n) {
      const unsigned short* vp = vt + vbase + (((long long)((n << 4) + col)) << 10) + kp0;
      u16x8 vb = *(const u16x8*)(vp);
      oacc[n] = mfma16x16x32(pa, vb, oacc[n]);
    }
  }

  #pragma unroll
  for (int n = 0; n < 4; ++n) {
    #pragma unroll
    for (int i = 0; i < 4; ++i) {
      int q = qt0 + (rg << 2) + i;
      size_t off = ((size_t)((b << 11) + (q << 1) + par)) * 512 + (h << 6) + (n << 4) + col;
      out[off] = f2bf(oacc[n][i] * inv[i]);
    }
  }
}

// ---------- launch ----------
extern "C" void kernel_launch(void* const* d_in, const int* in_sizes, int n_in,
                              void* d_out, int out_size, void* d_ws, size_t ws_size,
                              hipStream_t stream) {
  const float* x     = (const float*)d_in[0];
  const float* n1w   = (const float*)d_in[1];
  const float* n1b   = (const float*)d_in[2];
  const float* qkv_w = (const float*)d_in[3];
  const float* qkv_b = (const float*)d_in[4];
  const float* out_w = (const float*)d_in[5];
  const float* out_b = (const float*)d_in[6];
  const float* n2w   = (const float*)d_in[7];
  const float* n2b   = (const float*)d_in[8];
  const float* w1    = (const float*)d_in[9];
  const float* b1    = (const float*)d_in[10];
  const float* w2    = (const float*)d_in[11];
  const float* b2    = (const float*)d_in[12];

  char* ws = (char*)d_ws;
  unsigned short* wbf   = (unsigned short*)(ws);
  unsigned short* wq_bf = wbf;                              // [1536,512]
  unsigned short* wo_bf = (unsigned short*)(ws + 1572864);  // [512,512]
  unsigned short* w1_bf = (unsigned short*)(ws + 2097152);  // [2048,512]
  unsigned short* w2_bf = (unsigned short*)(ws + 4194304);  // [512,2048]
  unsigned short* h_bf  = (unsigned short*)(ws + 6291456);  // [4096,512]
  unsigned short* qkvb  = (unsigned short*)(ws + 10485760); // [4096,1536] bf16
  unsigned short* ao_bf = (unsigned short*)(ws + 23068672); // [4096,512] bf16
  float*          x1    = (float*)(ws + 27262976);          // [4096,512] fp32
  unsigned short* f1_bf = (unsigned short*)(ws + 10485760); // [4096,2048] aliases dead qkv+ao
  unsigned short* vt    = (unsigned short*)(ws + 35651584); // [2,2,8,64,1024] V^T bf16, 4MB
  float* outp = (float*)d_out;

  prep<<<4096, 256, 0, stream>>>(qkv_w, out_w, w1, w2, wbf, x, n1w, n1b, h_bf);
  gemm_bt<128, 64, 128, 0, 1><<<32 * 24, 256, 0, stream>>>(h_bf, wq_bf, qkv_b, nullptr,
                                                           nullptr, qkvb, vt, 4096, 1536, 512);
  attn_mfma<<<512, 256, 0, stream>>>(qkvb, vt, ao_bf);
  gemm_bt<64, 64, 128, 1, 0><<<64 * 8, 256, 0, stream>>>(ao_bf, wo_bf, out_b, x, x1,
                                                         nullptr, nullptr, 4096, 512, 512);
  ln_bf16<<<1024, 256, 0, stream>>>(x1, n2w, n2b, h_bf);
  gemm_bt<128, 64, 64, 2, 0><<<32 * 32, 256, 0, stream>>>(h_bf, w1_bf, b1, nullptr,
                                                          nullptr, f1_bf, nullptr, 4096, 2048, 512);
  gemm_bt<64, 64, 128, 1, 0><<<64 * 8, 256, 0, stream>>>(f1_bf, w2_bf, b2, x1, outp,
                                                         nullptr, nullptr, 4096, 512, 2048);
}